// Round 11
// baseline (3106.399 us; speedup 1.0000x reference)
//
#include <hip/hip_runtime.h>
#include <hip/hip_bf16.h>

// GIN GNN forward, R11 = R10 +
// 1) finalize fused into agg via last-block pattern: done-counter atomic,
//    last block reduces buckets with atomicAdd(p,0.0f) reads (memory-side
//    coherent; plain loads risk stale L2 since fp atomics bypass local L2)
//    and writes the BN affine. 3 dispatches removed.
// 2) agg edge loop x8 wide (32 edges/iter): 8 independent gathers in
//    flight per lane; deg<=32 -> single iteration.

#define NN 50000
#define NE 800000
#define FD 64
#define NG 256
#define CAP 64            // slots per node == wave width; max degree ~42
#define BN_EPS 1e-5f
#define GRIDA 12500       // agg blocks (4 nodes each)

#define NPART 8
#define PSIZE 6250        // nodes per XCD partition
#define ECHUNK 2048       // edges per build block
#define NCHUNK ((NE + ECHUNK - 1) / ECHUNK)     // 391
#define NBUILD (NCHUNK * NPART)                 // 3128
#define NCVT   ((NN * 16) / 256)                // 3125

__device__ __forceinline__ float4 dec4(uint2 a) {
    float4 f;
    f.x = __uint_as_float(a.x << 16);
    f.y = __uint_as_float(a.x & 0xFFFF0000u);
    f.z = __uint_as_float(a.y << 16);
    f.w = __uint_as_float(a.y & 0xFFFF0000u);
    return f;
}
__device__ __forceinline__ unsigned rbf(float f) {   // f32 -> bf16 bits (RNE)
    unsigned u = __float_as_uint(f);
    return (u + 0x7FFFu + ((u >> 16) & 1u)) >> 16;
}
__device__ __forceinline__ uint2 enc4(float4 v) {
    uint2 o;
    o.x = rbf(v.x) | (rbf(v.y) << 16);
    o.y = rbf(v.z) | (rbf(v.w) << 16);
    return o;
}

// ---------------- fused: XCD-partitioned slot build + x->bf16 cvt ----------
__global__ __launch_bounds__(256) void build_cvt_kernel(
    const int* __restrict__ src, const int* __restrict__ dst,
    const float* __restrict__ ew, int* __restrict__ cursor,
    unsigned* __restrict__ slots,
    const float4* __restrict__ xin, uint2* __restrict__ xout)
{
    int bid = blockIdx.x;
    int tid = threadIdx.x;
    if (bid < NBUILD) {
        int part  = bid & 7;            // consecutive blocks -> different XCDs
        int chunk = bid >> 3;
        int base  = chunk * ECHUNK;
        #pragma unroll
        for (int i = 0; i < ECHUNK; i += 256) {
            int e = base + i + tid;
            if (e < NE) {
                int d = dst[e];
                if (d / PSIZE == part) {    // this XCD owns this dst slice
                    int pos = atomicAdd(&cursor[d], 1) & (CAP - 1);
                    slots[(size_t)d * CAP + pos] =
                        ((unsigned)src[e] << 16) | rbf(ew[e]);
                }
            }
        }
    } else {
        int i = (bid - NBUILD) * 256 + tid;   // NN*16 = 800000 exact
        xout[i] = enc4(xin[i]);
    }
}

// ---------------- fused layer + last-block BN finalize ----------------
__global__ __launch_bounds__(256) void agg_layer_kernel(
    const uint2* __restrict__ h, const int* __restrict__ deg,
    const unsigned* __restrict__ slots, const float* __restrict__ affine,
    const float* __restrict__ W, const float* __restrict__ b,
    uint2* __restrict__ y, float* __restrict__ buckets, int* __restrict__ done,
    const float* __restrict__ gamma, const float* __restrict__ beta,
    float* __restrict__ affine_out, int relu_flag)
{
    __shared__ float Ws[FD * FD];       // 16 KB
    __shared__ float ps1[4][FD];
    __shared__ float ps2[4][FD];
    __shared__ int lastFlag;
    int tid  = threadIdx.x;
    int wave = tid >> 6, lane = tid & 63;
    int g = lane >> 4, l = lane & 15;
    int node = blockIdx.x * 4 + wave;   // 12500 * 4 == NN exact

    // stage W into LDS (coalesced float4)
    {
        float4* Wv = (float4*)Ws;
        const float4* Wg = (const float4*)W;
        #pragma unroll
        for (int i = 0; i < 4; i++) Wv[tid + 256 * i] = Wg[tid + 256 * i];
    }

    // slot row register-resident: lane i holds entry i (4B each)
    unsigned ms = slots[(size_t)node * CAP + lane];
    int dg = deg[node];                 // wave-uniform
    float4 self = dec4(h[(size_t)node * 16 + l]);
    if (dg > CAP) dg = CAP;

    __syncthreads();

    float4 acc = make_float4(0.f, 0.f, 0.f, 0.f);
    float wsum = 0.f;
    int nIter = (dg + 31) >> 5;         // WAVE-UNIFORM; 32 edges per iter
    for (int i = 0; i < nIter; i++) {
        unsigned m[8]; float w[8]; uint2 r[8];
        #pragma unroll
        for (int j = 0; j < 8; j++) {
            int e = 32 * i + 4 * j + g;
            int ee = (e < dg) ? e : 0;  // clamp to valid lane
            m[j] = (unsigned)__shfl((int)ms, ee, 64);
            float wj = __uint_as_float((m[j] & 0xFFFFu) << 16);
            w[j] = (e < dg) ? wj : 0.f; // mask invalid entries
        }
        #pragma unroll
        for (int j = 0; j < 8; j++)     // 8 independent gathers in flight
            r[j] = h[(size_t)(m[j] >> 16) * 16 + l];
        #pragma unroll
        for (int j = 0; j < 8; j++) {
            float4 v = dec4(r[j]);
            wsum += w[j];
            acc.x = fmaf(w[j], v.x, acc.x); acc.y = fmaf(w[j], v.y, acc.y);
            acc.z = fmaf(w[j], v.z, acc.z); acc.w = fmaf(w[j], v.w, acc.w);
        }
    }
    // reduce across the 4 edge groups -> replicated in all lanes
    acc.x += __shfl_xor(acc.x, 16, 64); acc.y += __shfl_xor(acc.y, 16, 64);
    acc.z += __shfl_xor(acc.z, 16, 64); acc.w += __shfl_xor(acc.w, 16, 64);
    wsum  += __shfl_xor(wsum, 16, 64);
    acc.x += __shfl_xor(acc.x, 32, 64); acc.y += __shfl_xor(acc.y, 32, 64);
    acc.z += __shfl_xor(acc.z, 32, 64); acc.w += __shfl_xor(acc.w, 32, 64);
    wsum  += __shfl_xor(wsum, 32, 64);

    float4 raw;
    raw.x = self.x + acc.x; raw.y = self.y + acc.y;
    raw.z = self.z + acc.z; raw.w = self.w + acc.w;

    float4 af = make_float4(1.f, 1.f, 1.f, 1.f);
    float4 cf = make_float4(0.f, 0.f, 0.f, 0.f);
    if (affine) {
        af = ((const float4*)affine)[l];
        cf = ((const float4*)(affine + FD))[l];
    }
    float sw = 1.0f + wsum;
    float4 hin;
    hin.x = fmaf(af.x, raw.x, cf.x * sw);
    hin.y = fmaf(af.y, raw.y, cf.y * sw);
    hin.z = fmaf(af.z, raw.z, cf.z * sw);
    hin.w = fmaf(af.w, raw.w, cf.w * sw);

    // matvec: group g covers k in [16g, 16g+16); W rows from LDS
    const float4* __restrict__ WsV = (const float4*)Ws;
    float4 yp = make_float4(0.f, 0.f, 0.f, 0.f);
    #pragma unroll
    for (int kk = 0; kk < 4; kk++) {
        int srcl = 4 * g + kk;           // lane holding features 4*srcl..+3
        float a0 = __shfl(hin.x, srcl, 64);
        float a1 = __shfl(hin.y, srcl, 64);
        float a2 = __shfl(hin.z, srcl, 64);
        float a3 = __shfl(hin.w, srcl, 64);
        int k0 = 16 * g + 4 * kk;
        float4 w0 = WsV[(k0 + 0) * 16 + l];
        float4 w1 = WsV[(k0 + 1) * 16 + l];
        float4 w2 = WsV[(k0 + 2) * 16 + l];
        float4 w3 = WsV[(k0 + 3) * 16 + l];
        yp.x = fmaf(a0, w0.x, yp.x); yp.y = fmaf(a0, w0.y, yp.y);
        yp.z = fmaf(a0, w0.z, yp.z); yp.w = fmaf(a0, w0.w, yp.w);
        yp.x = fmaf(a1, w1.x, yp.x); yp.y = fmaf(a1, w1.y, yp.y);
        yp.z = fmaf(a1, w1.z, yp.z); yp.w = fmaf(a1, w1.w, yp.w);
        yp.x = fmaf(a2, w2.x, yp.x); yp.y = fmaf(a2, w2.y, yp.y);
        yp.z = fmaf(a2, w2.z, yp.z); yp.w = fmaf(a2, w2.w, yp.w);
        yp.x = fmaf(a3, w3.x, yp.x); yp.y = fmaf(a3, w3.y, yp.y);
        yp.z = fmaf(a3, w3.z, yp.z); yp.w = fmaf(a3, w3.w, yp.w);
    }
    yp.x += __shfl_xor(yp.x, 16, 64); yp.y += __shfl_xor(yp.y, 16, 64);
    yp.z += __shfl_xor(yp.z, 16, 64); yp.w += __shfl_xor(yp.w, 16, 64);
    yp.x += __shfl_xor(yp.x, 32, 64); yp.y += __shfl_xor(yp.y, 32, 64);
    yp.z += __shfl_xor(yp.z, 32, 64); yp.w += __shfl_xor(yp.w, 32, 64);

    float4 bias = ((const float4*)b)[l];
    float4 yv;
    yv.x = yp.x + bias.x; yv.y = yp.y + bias.y;
    yv.z = yp.z + bias.z; yv.w = yp.w + bias.w;
    if (relu_flag) {
        yv.x = fmaxf(yv.x, 0.f); yv.y = fmaxf(yv.y, 0.f);
        yv.z = fmaxf(yv.z, 0.f); yv.w = fmaxf(yv.w, 0.f);
    }
    if (g == 0) {
        y[(size_t)node * 16 + l] = enc4(yv);
        ((float4*)&ps1[wave][0])[l] = yv;
        float4 sq;
        sq.x = yv.x * yv.x; sq.y = yv.y * yv.y;
        sq.z = yv.z * yv.z; sq.w = yv.w * yv.w;
        ((float4*)&ps2[wave][0])[l] = sq;
    }
    __syncthreads();
    if (tid < FD) {
        float a = ps1[0][tid] + ps1[1][tid] + ps1[2][tid] + ps1[3][tid];
        float q = ps2[0][tid] + ps2[1][tid] + ps2[2][tid] + ps2[3][tid];
        float* bk = buckets + (blockIdx.x & 63) * 128;
        atomicAdd(&bk[tid], a);
        atomicAdd(&bk[FD + tid], q);
    }

    // ---- last-block BN finalize ----
    __threadfence();                    // release bucket atomics
    if (tid == 0)
        lastFlag = (atomicAdd(done, 1) == GRIDA - 1);
    __syncthreads();                    // lastFlag block-uniform
    if (lastFlag) {
        __threadfence();                // acquire
        int f = tid & 63, q = tid >> 6;
        float S1 = 0.f, S2 = 0.f;
        #pragma unroll
        for (int i = 0; i < 16; i++) {
            int bkt = q * 16 + i;       // atomic reads: memory-side coherent
            S1 += atomicAdd(&buckets[bkt * 128 + f], 0.0f);
            S2 += atomicAdd(&buckets[bkt * 128 + FD + f], 0.0f);
        }
        ps1[q][f] = S1;
        ps2[q][f] = S2;
        __syncthreads();
        if (tid < FD) {
            float s1 = ps1[0][tid] + ps1[1][tid] + ps1[2][tid] + ps1[3][tid];
            float s2 = ps2[0][tid] + ps2[1][tid] + ps2[2][tid] + ps2[3][tid];
            float mu  = s1 * (1.f / NN);
            float var = s2 * (1.f / NN) - mu * mu;
            float a = gamma[tid] * rsqrtf(var + BN_EPS);
            affine_out[tid]      = a;
            affine_out[FD + tid] = beta[tid] - mu * a;
        }
    }
}

// ---------------- fused pool + head ----------------
__global__ __launch_bounds__(256) void pool_head_kernel(
    const uint2* __restrict__ y, const int* __restrict__ batch,
    const float* __restrict__ affine3,
    const float* __restrict__ fcW1, const float* __restrict__ fcb1,
    const float* __restrict__ fcW2, const float* __restrict__ fcb2,
    float* __restrict__ out)
{
    __shared__ float red[16][FD];
    __shared__ int bounds[2];
    int tid = threadIdx.x;
    int g = blockIdx.x;
    if (tid < 2) {
        int target = g + tid;           // lower_bound(batch, target)
        int lo = 0, hi = NN;
        while (lo < hi) {
            int mid = (lo + hi) >> 1;
            if (batch[mid] < target) lo = mid + 1; else hi = mid;
        }
        bounds[tid] = lo;
    }
    __syncthreads();
    int s = bounds[0], e = bounds[1];
    int l = tid & 15, r = tid >> 4;
    float4 acc = make_float4(0.f, 0.f, 0.f, 0.f);
    for (int n = s + r; n < e; n += 16) {
        float4 v = dec4(y[(size_t)n * 16 + l]);
        acc.x += v.x; acc.y += v.y; acc.z += v.z; acc.w += v.w;
    }
    ((float4*)&red[r][0])[l] = acc;
    __syncthreads();
    for (int off = 8; off > 0; off >>= 1) {
        if (r < off) {
            float4 a = ((float4*)&red[r][0])[l];
            float4 o = ((float4*)&red[r + off][0])[l];
            a.x += o.x; a.y += o.y; a.z += o.z; a.w += o.w;
            ((float4*)&red[r][0])[l] = a;
        }
        __syncthreads();
    }
    if (tid < 64) {                      // wave-uniform branch: shuffles safe
        float cnt = (float)(e - s);
        float p = red[0][tid];
        p = fmaf(affine3[tid], p, affine3[FD + tid] * cnt);  // BN3
        p = fmaxf(p, 0.f);
        float acc1 = fcb1[tid];
        #pragma unroll
        for (int k = 0; k < FD; k++) {
            float pk = __shfl(p, k, 64);
            acc1 = fmaf(pk, fcW1[k * FD + tid], acc1);
        }
        acc1 = fmaxf(acc1, 0.f);
        float prod = acc1 * fcW2[tid];
        #pragma unroll
        for (int off = 32; off > 0; off >>= 1)
            prod += __shfl_xor(prod, off, 64);
        if (tid == 0) out[g] = prod + fcb2[0];
    }
}

extern "C" void kernel_launch(void* const* d_in, const int* in_sizes, int n_in,
                              void* d_out, int out_size, void* d_ws, size_t ws_size,
                              hipStream_t stream) {
    const float* x     = (const float*)d_in[0];
    const int*   ei    = (const int*)d_in[1];
    const float* ew    = (const float*)d_in[2];
    const int*   batch = (const int*)d_in[3];
    const float* W1 = (const float*)d_in[4],  *b1 = (const float*)d_in[5];
    const float* W2 = (const float*)d_in[6],  *b2 = (const float*)d_in[7];
    const float* W3 = (const float*)d_in[8],  *b3 = (const float*)d_in[9];
    const float* fcW1 = (const float*)d_in[10], *fcb1 = (const float*)d_in[11];
    const float* fcW2 = (const float*)d_in[12], *fcb2 = (const float*)d_in[13];
    const float* g1 = (const float*)d_in[14], *be1 = (const float*)d_in[15];
    const float* g2 = (const float*)d_in[16], *be2 = (const float*)d_in[17];
    const float* g3 = (const float*)d_in[18], *be3 = (const float*)d_in[19];
    float* out = (float*)d_out;

    const int* srcp = ei;
    const int* dstp = ei + NE;

    char* ws = (char*)d_ws;
    size_t off = 0;
    auto take = [&](size_t bytes) -> char* {
        char* p = ws + off;
        off += (bytes + 255) & ~(size_t)255;
        return p;
    };
    uint2*    xbf   = (uint2*)   take((size_t)NN * FD * 2);    // 6.4 MB
    uint2*    bufA  = (uint2*)   take((size_t)NN * FD * 2);    // y1, then y3
    uint2*    bufB  = (uint2*)   take((size_t)NN * FD * 2);    // y2
    unsigned* slots = (unsigned*)take((size_t)NN * CAP * 4);   // 12.8 MB
    float*    affine= (float*)   take((size_t)3 * 2 * FD * 4);
    size_t zero_base = off;
    int*      cursor= (int*)     take((size_t)NN * 4);         // becomes deg
    float*    buckets=(float*)   take((size_t)3 * 64 * 128 * 4);
    int*      done  = (int*)     take((size_t)4 * 4);
    size_t zero_bytes = off - zero_base;
    (void)ws_size; (void)n_in; (void)in_sizes; (void)out_size;

    hipMemsetAsync(ws + zero_base, 0, zero_bytes, stream);

    build_cvt_kernel<<<NBUILD + NCVT, 256, 0, stream>>>(srcp, dstp, ew,
                                                        cursor, slots,
                                                        (const float4*)x, xbf);

    float* bk1 = buckets + 0 * 64 * 128;
    float* bk2 = buckets + 1 * 64 * 128;
    float* bk3 = buckets + 2 * 64 * 128;
    float* af1 = affine + 0 * 128;
    float* af2 = affine + 1 * 128;
    float* af3 = affine + 2 * 128;

    agg_layer_kernel<<<GRIDA, 256, 0, stream>>>(xbf, cursor, slots,
                                                nullptr, W1, b1, bufA,
                                                bk1, done + 0, g1, be1, af1, 1);
    agg_layer_kernel<<<GRIDA, 256, 0, stream>>>(bufA, cursor, slots,
                                                af1, W2, b2, bufB,
                                                bk2, done + 1, g2, be2, af2, 1);
    agg_layer_kernel<<<GRIDA, 256, 0, stream>>>(bufB, cursor, slots,
                                                af2, W3, b3, bufA,
                                                bk3, done + 2, g3, be3, af3, 0);
    pool_head_kernel<<<NG, 256, 0, stream>>>(bufA, batch, af3,
                                             fcW1, fcb1, fcW2, fcb2, out);
}

// Round 12
// 271.433 us; speedup vs baseline: 11.4444x; 11.4444x over previous
//
#include <hip/hip_runtime.h>
#include <hip/hip_bf16.h>

// GIN GNN forward, R12 = R10 structure (separate finalize kernels, NO device
// fences) + x8-wide edge loop from R11.
// R11 lesson: last-block finalize required __threadfence() in all 12500
// blocks -> L2 writeback/invalidate per wave on non-coherent-XCD CDNA4 ->
// gathers lost all L2 locality, agg 40us -> 1000us. Tiny extra dispatches
// beat device-scope fences.

#define NN 50000
#define NE 800000
#define FD 64
#define NG 256
#define CAP 64            // slots per node == wave width; max degree ~42
#define BN_EPS 1e-5f

#define NPART 8
#define PSIZE 6250        // nodes per XCD partition
#define ECHUNK 2048       // edges per build block
#define NCHUNK ((NE + ECHUNK - 1) / ECHUNK)     // 391
#define NBUILD (NCHUNK * NPART)                 // 3128
#define NCVT   ((NN * 16) / 256)                // 3125

__device__ __forceinline__ float4 dec4(uint2 a) {
    float4 f;
    f.x = __uint_as_float(a.x << 16);
    f.y = __uint_as_float(a.x & 0xFFFF0000u);
    f.z = __uint_as_float(a.y << 16);
    f.w = __uint_as_float(a.y & 0xFFFF0000u);
    return f;
}
__device__ __forceinline__ unsigned rbf(float f) {   // f32 -> bf16 bits (RNE)
    unsigned u = __float_as_uint(f);
    return (u + 0x7FFFu + ((u >> 16) & 1u)) >> 16;
}
__device__ __forceinline__ uint2 enc4(float4 v) {
    uint2 o;
    o.x = rbf(v.x) | (rbf(v.y) << 16);
    o.y = rbf(v.z) | (rbf(v.w) << 16);
    return o;
}

// ---------------- fused: XCD-partitioned slot build + x->bf16 cvt ----------
__global__ __launch_bounds__(256) void build_cvt_kernel(
    const int* __restrict__ src, const int* __restrict__ dst,
    const float* __restrict__ ew, int* __restrict__ cursor,
    unsigned* __restrict__ slots,
    const float4* __restrict__ xin, uint2* __restrict__ xout)
{
    int bid = blockIdx.x;
    int tid = threadIdx.x;
    if (bid < NBUILD) {
        int part  = bid & 7;            // consecutive blocks -> different XCDs
        int chunk = bid >> 3;
        int base  = chunk * ECHUNK;
        #pragma unroll
        for (int i = 0; i < ECHUNK; i += 256) {
            int e = base + i + tid;
            if (e < NE) {
                int d = dst[e];
                if (d / PSIZE == part) {    // this XCD owns this dst slice
                    int pos = atomicAdd(&cursor[d], 1) & (CAP - 1);
                    slots[(size_t)d * CAP + pos] =
                        ((unsigned)src[e] << 16) | rbf(ew[e]);
                }
            }
        }
    } else {
        int i = (bid - NBUILD) * 256 + tid;   // NN*16 = 800000 exact
        xout[i] = enc4(xin[i]);
    }
}

// ---------------- fused layer ----------------
// 1 node per wave; lane = (g = edge group, l = feature quad).
// hin = af (.) (y[node] + sum_e w*y[src]) + cf * (1 + sum_e w)
// y = [relu]( hin @ W + b ), + bucketed BN stats of y.
__global__ __launch_bounds__(256) void agg_layer_kernel(
    const uint2* __restrict__ h, const int* __restrict__ deg,
    const unsigned* __restrict__ slots, const float* __restrict__ affine,
    const float* __restrict__ W, const float* __restrict__ b,
    uint2* __restrict__ y, float* __restrict__ buckets, int relu_flag)
{
    __shared__ float Ws[FD * FD];       // 16 KB
    __shared__ float ps1[4][FD];
    __shared__ float ps2[4][FD];
    int tid  = threadIdx.x;
    int wave = tid >> 6, lane = tid & 63;
    int g = lane >> 4, l = lane & 15;
    int node = blockIdx.x * 4 + wave;   // 12500 * 4 == NN exact

    // stage W into LDS (coalesced float4)
    {
        float4* Wv = (float4*)Ws;
        const float4* Wg = (const float4*)W;
        #pragma unroll
        for (int i = 0; i < 4; i++) Wv[tid + 256 * i] = Wg[tid + 256 * i];
    }

    // slot row register-resident: lane i holds entry i (4B each)
    unsigned ms = slots[(size_t)node * CAP + lane];
    int dg = deg[node];                 // wave-uniform
    float4 self = dec4(h[(size_t)node * 16 + l]);
    if (dg > CAP) dg = CAP;

    __syncthreads();

    float4 acc = make_float4(0.f, 0.f, 0.f, 0.f);
    float wsum = 0.f;
    int nIter = (dg + 31) >> 5;         // WAVE-UNIFORM; 32 edges per iter
    for (int i = 0; i < nIter; i++) {
        unsigned m[8]; float w[8]; uint2 r[8];
        #pragma unroll
        for (int j = 0; j < 8; j++) {
            int e = 32 * i + 4 * j + g;
            int ee = (e < dg) ? e : 0;  // clamp to valid lane
            m[j] = (unsigned)__shfl((int)ms, ee, 64);
            float wj = __uint_as_float((m[j] & 0xFFFFu) << 16);
            w[j] = (e < dg) ? wj : 0.f; // mask invalid entries
        }
        #pragma unroll
        for (int j = 0; j < 8; j++)     // 8 independent gathers in flight
            r[j] = h[(size_t)(m[j] >> 16) * 16 + l];
        #pragma unroll
        for (int j = 0; j < 8; j++) {
            float4 v = dec4(r[j]);
            wsum += w[j];
            acc.x = fmaf(w[j], v.x, acc.x); acc.y = fmaf(w[j], v.y, acc.y);
            acc.z = fmaf(w[j], v.z, acc.z); acc.w = fmaf(w[j], v.w, acc.w);
        }
    }
    // reduce across the 4 edge groups -> replicated in all lanes
    acc.x += __shfl_xor(acc.x, 16, 64); acc.y += __shfl_xor(acc.y, 16, 64);
    acc.z += __shfl_xor(acc.z, 16, 64); acc.w += __shfl_xor(acc.w, 16, 64);
    wsum  += __shfl_xor(wsum, 16, 64);
    acc.x += __shfl_xor(acc.x, 32, 64); acc.y += __shfl_xor(acc.y, 32, 64);
    acc.z += __shfl_xor(acc.z, 32, 64); acc.w += __shfl_xor(acc.w, 32, 64);
    wsum  += __shfl_xor(wsum, 32, 64);

    float4 raw;
    raw.x = self.x + acc.x; raw.y = self.y + acc.y;
    raw.z = self.z + acc.z; raw.w = self.w + acc.w;

    float4 af = make_float4(1.f, 1.f, 1.f, 1.f);
    float4 cf = make_float4(0.f, 0.f, 0.f, 0.f);
    if (affine) {
        af = ((const float4*)affine)[l];
        cf = ((const float4*)(affine + FD))[l];
    }
    float sw = 1.0f + wsum;
    float4 hin;
    hin.x = fmaf(af.x, raw.x, cf.x * sw);
    hin.y = fmaf(af.y, raw.y, cf.y * sw);
    hin.z = fmaf(af.z, raw.z, cf.z * sw);
    hin.w = fmaf(af.w, raw.w, cf.w * sw);

    // matvec: group g covers k in [16g, 16g+16); W rows from LDS
    const float4* __restrict__ WsV = (const float4*)Ws;
    float4 yp = make_float4(0.f, 0.f, 0.f, 0.f);
    #pragma unroll
    for (int kk = 0; kk < 4; kk++) {
        int srcl = 4 * g + kk;           // lane holding features 4*srcl..+3
        float a0 = __shfl(hin.x, srcl, 64);
        float a1 = __shfl(hin.y, srcl, 64);
        float a2 = __shfl(hin.z, srcl, 64);
        float a3 = __shfl(hin.w, srcl, 64);
        int k0 = 16 * g + 4 * kk;
        float4 w0 = WsV[(k0 + 0) * 16 + l];
        float4 w1 = WsV[(k0 + 1) * 16 + l];
        float4 w2 = WsV[(k0 + 2) * 16 + l];
        float4 w3 = WsV[(k0 + 3) * 16 + l];
        yp.x = fmaf(a0, w0.x, yp.x); yp.y = fmaf(a0, w0.y, yp.y);
        yp.z = fmaf(a0, w0.z, yp.z); yp.w = fmaf(a0, w0.w, yp.w);
        yp.x = fmaf(a1, w1.x, yp.x); yp.y = fmaf(a1, w1.y, yp.y);
        yp.z = fmaf(a1, w1.z, yp.z); yp.w = fmaf(a1, w1.w, yp.w);
        yp.x = fmaf(a2, w2.x, yp.x); yp.y = fmaf(a2, w2.y, yp.y);
        yp.z = fmaf(a2, w2.z, yp.z); yp.w = fmaf(a2, w2.w, yp.w);
        yp.x = fmaf(a3, w3.x, yp.x); yp.y = fmaf(a3, w3.y, yp.y);
        yp.z = fmaf(a3, w3.z, yp.z); yp.w = fmaf(a3, w3.w, yp.w);
    }
    yp.x += __shfl_xor(yp.x, 16, 64); yp.y += __shfl_xor(yp.y, 16, 64);
    yp.z += __shfl_xor(yp.z, 16, 64); yp.w += __shfl_xor(yp.w, 16, 64);
    yp.x += __shfl_xor(yp.x, 32, 64); yp.y += __shfl_xor(yp.y, 32, 64);
    yp.z += __shfl_xor(yp.z, 32, 64); yp.w += __shfl_xor(yp.w, 32, 64);

    float4 bias = ((const float4*)b)[l];
    float4 yv;
    yv.x = yp.x + bias.x; yv.y = yp.y + bias.y;
    yv.z = yp.z + bias.z; yv.w = yp.w + bias.w;
    if (relu_flag) {
        yv.x = fmaxf(yv.x, 0.f); yv.y = fmaxf(yv.y, 0.f);
        yv.z = fmaxf(yv.z, 0.f); yv.w = fmaxf(yv.w, 0.f);
    }
    if (g == 0) {
        y[(size_t)node * 16 + l] = enc4(yv);
        ((float4*)&ps1[wave][0])[l] = yv;
        float4 sq;
        sq.x = yv.x * yv.x; sq.y = yv.y * yv.y;
        sq.z = yv.z * yv.z; sq.w = yv.w * yv.w;
        ((float4*)&ps2[wave][0])[l] = sq;
    }
    __syncthreads();
    if (tid < FD) {
        float a = ps1[0][tid] + ps1[1][tid] + ps1[2][tid] + ps1[3][tid];
        float q = ps2[0][tid] + ps2[1][tid] + ps2[2][tid] + ps2[3][tid];
        float* bk = buckets + (blockIdx.x & 63) * 128;
        atomicAdd(&bk[tid], a);
        atomicAdd(&bk[FD + tid], q);
    }
}

// buckets -> BN affine coefficients (af, cf). 256 threads.
__global__ __launch_bounds__(256) void finalize_kernel(
    const float* __restrict__ buckets, const float* __restrict__ gamma,
    const float* __restrict__ beta, float* __restrict__ affine)
{
    __shared__ float part[4][2][FD];
    int tid = threadIdx.x;
    int f = tid & 63, q = tid >> 6;
    float S1 = 0.f, S2 = 0.f;
    #pragma unroll
    for (int i = 0; i < 16; i++) {
        int bkt = q * 16 + i;
        S1 += buckets[bkt * 128 + f];
        S2 += buckets[bkt * 128 + FD + f];
    }
    part[q][0][f] = S1;
    part[q][1][f] = S2;
    __syncthreads();
    if (tid < FD) {
        float s1 = part[0][0][tid] + part[1][0][tid] + part[2][0][tid] + part[3][0][tid];
        float s2 = part[0][1][tid] + part[1][1][tid] + part[2][1][tid] + part[3][1][tid];
        float mu  = s1 * (1.f / NN);
        float var = s2 * (1.f / NN) - mu * mu;
        float a = gamma[tid] * rsqrtf(var + BN_EPS);
        affine[tid]      = a;
        affine[FD + tid] = beta[tid] - mu * a;
    }
}

// ---------------- fused pool + head ----------------
__global__ __launch_bounds__(256) void pool_head_kernel(
    const uint2* __restrict__ y, const int* __restrict__ batch,
    const float* __restrict__ affine3,
    const float* __restrict__ fcW1, const float* __restrict__ fcb1,
    const float* __restrict__ fcW2, const float* __restrict__ fcb2,
    float* __restrict__ out)
{
    __shared__ float red[16][FD];
    __shared__ int bounds[2];
    int tid = threadIdx.x;
    int g = blockIdx.x;
    if (tid < 2) {
        int target = g + tid;           // lower_bound(batch, target)
        int lo = 0, hi = NN;
        while (lo < hi) {
            int mid = (lo + hi) >> 1;
            if (batch[mid] < target) lo = mid + 1; else hi = mid;
        }
        bounds[tid] = lo;
    }
    __syncthreads();
    int s = bounds[0], e = bounds[1];
    int l = tid & 15, r = tid >> 4;
    float4 acc = make_float4(0.f, 0.f, 0.f, 0.f);
    for (int n = s + r; n < e; n += 16) {
        float4 v = dec4(y[(size_t)n * 16 + l]);
        acc.x += v.x; acc.y += v.y; acc.z += v.z; acc.w += v.w;
    }
    ((float4*)&red[r][0])[l] = acc;
    __syncthreads();
    for (int off = 8; off > 0; off >>= 1) {
        if (r < off) {
            float4 a = ((float4*)&red[r][0])[l];
            float4 o = ((float4*)&red[r + off][0])[l];
            a.x += o.x; a.y += o.y; a.z += o.z; a.w += o.w;
            ((float4*)&red[r][0])[l] = a;
        }
        __syncthreads();
    }
    if (tid < 64) {                      // wave-uniform branch: shuffles safe
        float cnt = (float)(e - s);
        float p = red[0][tid];
        p = fmaf(affine3[tid], p, affine3[FD + tid] * cnt);  // BN3
        p = fmaxf(p, 0.f);
        float acc1 = fcb1[tid];
        #pragma unroll
        for (int k = 0; k < FD; k++) {
            float pk = __shfl(p, k, 64);
            acc1 = fmaf(pk, fcW1[k * FD + tid], acc1);
        }
        acc1 = fmaxf(acc1, 0.f);
        float prod = acc1 * fcW2[tid];
        #pragma unroll
        for (int off = 32; off > 0; off >>= 1)
            prod += __shfl_xor(prod, off, 64);
        if (tid == 0) out[g] = prod + fcb2[0];
    }
}

extern "C" void kernel_launch(void* const* d_in, const int* in_sizes, int n_in,
                              void* d_out, int out_size, void* d_ws, size_t ws_size,
                              hipStream_t stream) {
    const float* x     = (const float*)d_in[0];
    const int*   ei    = (const int*)d_in[1];
    const float* ew    = (const float*)d_in[2];
    const int*   batch = (const int*)d_in[3];
    const float* W1 = (const float*)d_in[4],  *b1 = (const float*)d_in[5];
    const float* W2 = (const float*)d_in[6],  *b2 = (const float*)d_in[7];
    const float* W3 = (const float*)d_in[8],  *b3 = (const float*)d_in[9];
    const float* fcW1 = (const float*)d_in[10], *fcb1 = (const float*)d_in[11];
    const float* fcW2 = (const float*)d_in[12], *fcb2 = (const float*)d_in[13];
    const float* g1 = (const float*)d_in[14], *be1 = (const float*)d_in[15];
    const float* g2 = (const float*)d_in[16], *be2 = (const float*)d_in[17];
    const float* g3 = (const float*)d_in[18], *be3 = (const float*)d_in[19];
    float* out = (float*)d_out;

    const int* srcp = ei;
    const int* dstp = ei + NE;

    char* ws = (char*)d_ws;
    size_t off = 0;
    auto take = [&](size_t bytes) -> char* {
        char* p = ws + off;
        off += (bytes + 255) & ~(size_t)255;
        return p;
    };
    uint2*    xbf   = (uint2*)   take((size_t)NN * FD * 2);    // 6.4 MB
    uint2*    bufA  = (uint2*)   take((size_t)NN * FD * 2);    // y1, then y3
    uint2*    bufB  = (uint2*)   take((size_t)NN * FD * 2);    // y2
    unsigned* slots = (unsigned*)take((size_t)NN * CAP * 4);   // 12.8 MB
    float*    affine= (float*)   take((size_t)3 * 2 * FD * 4);
    size_t zero_base = off;
    int*      cursor= (int*)     take((size_t)NN * 4);         // becomes deg
    float*    buckets=(float*)   take((size_t)3 * 64 * 128 * 4);
    size_t zero_bytes = off - zero_base;
    (void)ws_size; (void)n_in; (void)in_sizes; (void)out_size;

    hipMemsetAsync(ws + zero_base, 0, zero_bytes, stream);

    build_cvt_kernel<<<NBUILD + NCVT, 256, 0, stream>>>(srcp, dstp, ew,
                                                        cursor, slots,
                                                        (const float4*)x, xbf);

    const int gridA = NN / 4;   // 12500 blocks, 4 nodes (waves) each

    float* bk1 = buckets + 0 * 64 * 128;
    float* bk2 = buckets + 1 * 64 * 128;
    float* bk3 = buckets + 2 * 64 * 128;
    float* af1 = affine + 0 * 128;
    float* af2 = affine + 1 * 128;
    float* af3 = affine + 2 * 128;

    agg_layer_kernel<<<gridA, 256, 0, stream>>>(xbf, cursor, slots,
                                                nullptr, W1, b1, bufA, bk1, 1);
    finalize_kernel<<<1, 256, 0, stream>>>(bk1, g1, be1, af1);
    agg_layer_kernel<<<gridA, 256, 0, stream>>>(bufA, cursor, slots,
                                                af1, W2, b2, bufB, bk2, 1);
    finalize_kernel<<<1, 256, 0, stream>>>(bk2, g2, be2, af2);
    agg_layer_kernel<<<gridA, 256, 0, stream>>>(bufB, cursor, slots,
                                                af2, W3, b3, bufA, bk3, 0);
    finalize_kernel<<<1, 256, 0, stream>>>(bk3, g3, be3, af3);
    pool_head_kernel<<<NG, 256, 0, stream>>>(bufA, batch, af3,
                                             fcW1, fcb1, fcW2, fcb2, out);
}

// Round 13
// 270.846 us; speedup vs baseline: 11.4693x; 1.0022x over previous
//
#include <hip/hip_runtime.h>
#include <hip/hip_bf16.h>

// GIN GNN forward, R13 = R12 +
// 1) hybrid edge loop: deg<=16 -> single 16-edge pass (57% of nodes, cuts
//    masked-edge VALU waste; agg is now VALU-bound, 60% busy in R12).
// 2) finalize kernels eliminated: each agg / pool_head computes the PREV
//    layer's BN affine in its block prologue from the bucket array
//    (dispatch boundary = visibility; no device fences - R11 lesson).
//    9 dispatches -> 6.

#define NN 50000
#define NE 800000
#define FD 64
#define NG 256
#define CAP 64            // slots per node == wave width; max degree ~42
#define BN_EPS 1e-5f

#define NPART 8
#define PSIZE 6250        // nodes per XCD partition
#define ECHUNK 2048       // edges per build block
#define NCHUNK ((NE + ECHUNK - 1) / ECHUNK)     // 391
#define NBUILD (NCHUNK * NPART)                 // 3128
#define NCVT   ((NN * 16) / 256)                // 3125

__device__ __forceinline__ float4 dec4(uint2 a) {
    float4 f;
    f.x = __uint_as_float(a.x << 16);
    f.y = __uint_as_float(a.x & 0xFFFF0000u);
    f.z = __uint_as_float(a.y << 16);
    f.w = __uint_as_float(a.y & 0xFFFF0000u);
    return f;
}
__device__ __forceinline__ unsigned rbf(float f) {   // f32 -> bf16 bits (RNE)
    unsigned u = __float_as_uint(f);
    return (u + 0x7FFFu + ((u >> 16) & 1u)) >> 16;
}
__device__ __forceinline__ uint2 enc4(float4 v) {
    uint2 o;
    o.x = rbf(v.x) | (rbf(v.y) << 16);
    o.y = rbf(v.z) | (rbf(v.w) << 16);
    return o;
}

// ---------------- fused: XCD-partitioned slot build + x->bf16 cvt ----------
__global__ __launch_bounds__(256) void build_cvt_kernel(
    const int* __restrict__ src, const int* __restrict__ dst,
    const float* __restrict__ ew, int* __restrict__ cursor,
    unsigned* __restrict__ slots,
    const float4* __restrict__ xin, uint2* __restrict__ xout)
{
    int bid = blockIdx.x;
    int tid = threadIdx.x;
    if (bid < NBUILD) {
        int part  = bid & 7;            // consecutive blocks -> different XCDs
        int chunk = bid >> 3;
        int base  = chunk * ECHUNK;
        #pragma unroll
        for (int i = 0; i < ECHUNK; i += 256) {
            int e = base + i + tid;
            if (e < NE) {
                int d = dst[e];
                if (d / PSIZE == part) {    // this XCD owns this dst slice
                    int pos = atomicAdd(&cursor[d], 1) & (CAP - 1);
                    slots[(size_t)d * CAP + pos] =
                        ((unsigned)src[e] << 16) | rbf(ew[e]);
                }
            }
        }
    } else {
        int i = (bid - NBUILD) * 256 + tid;   // NN*16 = 800000 exact
        xout[i] = enc4(xin[i]);
    }
}

// ---------------- fused layer (+ prologue BN affine of PREV layer) --------
// 1 node per wave; lane = (g = edge group, l = feature quad).
// hin = af (.) (y[node] + sum_e w*y[src]) + cf * (1 + sum_e w)
// y = [relu]( hin @ W + b ), + bucketed BN stats of y.
__global__ __launch_bounds__(256) void agg_layer_kernel(
    const uint2* __restrict__ h, const int* __restrict__ deg,
    const unsigned* __restrict__ slots,
    const float* __restrict__ prev_buckets,     // null for layer 1
    const float* __restrict__ prev_gamma, const float* __restrict__ prev_beta,
    const float* __restrict__ W, const float* __restrict__ b,
    uint2* __restrict__ y, float* __restrict__ buckets, int relu_flag)
{
    __shared__ float Ws[FD * FD];       // 16 KB
    __shared__ float ps1[4][FD];
    __shared__ float ps2[4][FD];
    __shared__ float afs[FD], cfs[FD];
    int tid  = threadIdx.x;
    int wave = tid >> 6, lane = tid & 63;
    int g = lane >> 4, l = lane & 15;
    int node = blockIdx.x * 4 + wave;   // 12500 * 4 == NN exact

    // stage W into LDS (coalesced float4)
    {
        float4* Wv = (float4*)Ws;
        const float4* Wg = (const float4*)W;
        #pragma unroll
        for (int i = 0; i < 4; i++) Wv[tid + 256 * i] = Wg[tid + 256 * i];
    }

    // slot row register-resident: lane i holds entry i (4B each)
    unsigned ms = slots[(size_t)node * CAP + lane];
    int dg = deg[node];                 // wave-uniform
    float4 self = dec4(h[(size_t)node * 16 + l]);
    if (dg > CAP) dg = CAP;

    // prologue: reduce prev layer's buckets -> BN affine (kernel-uniform if)
    if (prev_buckets) {
        int f = tid & 63, q = tid >> 6;
        float S1 = 0.f, S2 = 0.f;
        #pragma unroll
        for (int i = 0; i < 16; i++) {
            int bkt = q * 16 + i;
            S1 += prev_buckets[bkt * 128 + f];
            S2 += prev_buckets[bkt * 128 + FD + f];
        }
        ps1[q][f] = S1;
        ps2[q][f] = S2;
    }
    __syncthreads();
    if (prev_buckets && tid < FD) {
        float s1 = ps1[0][tid] + ps1[1][tid] + ps1[2][tid] + ps1[3][tid];
        float s2 = ps2[0][tid] + ps2[1][tid] + ps2[2][tid] + ps2[3][tid];
        float mu  = s1 * (1.f / NN);
        float var = s2 * (1.f / NN) - mu * mu;
        float a = prev_gamma[tid] * rsqrtf(var + BN_EPS);
        afs[tid] = a;
        cfs[tid] = prev_beta[tid] - mu * a;
    }
    __syncthreads();

    float4 af = make_float4(1.f, 1.f, 1.f, 1.f);
    float4 cf = make_float4(0.f, 0.f, 0.f, 0.f);
    if (prev_buckets) {
        af = ((const float4*)afs)[l];
        cf = ((const float4*)cfs)[l];
    }

    float4 acc = make_float4(0.f, 0.f, 0.f, 0.f);
    float wsum = 0.f;
    if (dg <= 16) {
        // single 16-edge pass: 4 gathers in flight, minimal masked waste
        unsigned m[4]; float w[4]; uint2 r[4];
        #pragma unroll
        for (int j = 0; j < 4; j++) {
            int e = 4 * j + g;
            int ee = (e < dg) ? e : 0;
            m[j] = (unsigned)__shfl((int)ms, ee, 64);
            float wj = __uint_as_float(m[j] << 16);
            w[j] = (e < dg) ? wj : 0.f;
        }
        #pragma unroll
        for (int j = 0; j < 4; j++)
            r[j] = h[(size_t)(m[j] >> 16) * 16 + l];
        #pragma unroll
        for (int j = 0; j < 4; j++) {
            float4 v = dec4(r[j]);
            wsum += w[j];
            acc.x = fmaf(w[j], v.x, acc.x); acc.y = fmaf(w[j], v.y, acc.y);
            acc.z = fmaf(w[j], v.z, acc.z); acc.w = fmaf(w[j], v.w, acc.w);
        }
    } else {
        int nIter = (dg + 31) >> 5;     // WAVE-UNIFORM; 32 edges per iter
        for (int i = 0; i < nIter; i++) {
            unsigned m[8]; float w[8]; uint2 r[8];
            #pragma unroll
            for (int j = 0; j < 8; j++) {
                int e = 32 * i + 4 * j + g;
                int ee = (e < dg) ? e : 0;
                m[j] = (unsigned)__shfl((int)ms, ee, 64);
                float wj = __uint_as_float(m[j] << 16);
                w[j] = (e < dg) ? wj : 0.f;
            }
            #pragma unroll
            for (int j = 0; j < 8; j++)  // 8 independent gathers in flight
                r[j] = h[(size_t)(m[j] >> 16) * 16 + l];
            #pragma unroll
            for (int j = 0; j < 8; j++) {
                float4 v = dec4(r[j]);
                wsum += w[j];
                acc.x = fmaf(w[j], v.x, acc.x); acc.y = fmaf(w[j], v.y, acc.y);
                acc.z = fmaf(w[j], v.z, acc.z); acc.w = fmaf(w[j], v.w, acc.w);
            }
        }
    }
    // reduce across the 4 edge groups -> replicated in all lanes
    acc.x += __shfl_xor(acc.x, 16, 64); acc.y += __shfl_xor(acc.y, 16, 64);
    acc.z += __shfl_xor(acc.z, 16, 64); acc.w += __shfl_xor(acc.w, 16, 64);
    wsum  += __shfl_xor(wsum, 16, 64);
    acc.x += __shfl_xor(acc.x, 32, 64); acc.y += __shfl_xor(acc.y, 32, 64);
    acc.z += __shfl_xor(acc.z, 32, 64); acc.w += __shfl_xor(acc.w, 32, 64);
    wsum  += __shfl_xor(wsum, 32, 64);

    float4 raw;
    raw.x = self.x + acc.x; raw.y = self.y + acc.y;
    raw.z = self.z + acc.z; raw.w = self.w + acc.w;

    float sw = 1.0f + wsum;
    float4 hin;
    hin.x = fmaf(af.x, raw.x, cf.x * sw);
    hin.y = fmaf(af.y, raw.y, cf.y * sw);
    hin.z = fmaf(af.z, raw.z, cf.z * sw);
    hin.w = fmaf(af.w, raw.w, cf.w * sw);

    // matvec: group g covers k in [16g, 16g+16); W rows from LDS
    const float4* __restrict__ WsV = (const float4*)Ws;
    float4 yp = make_float4(0.f, 0.f, 0.f, 0.f);
    #pragma unroll
    for (int kk = 0; kk < 4; kk++) {
        int srcl = 4 * g + kk;           // lane holding features 4*srcl..+3
        float a0 = __shfl(hin.x, srcl, 64);
        float a1 = __shfl(hin.y, srcl, 64);
        float a2 = __shfl(hin.z, srcl, 64);
        float a3 = __shfl(hin.w, srcl, 64);
        int k0 = 16 * g + 4 * kk;
        float4 w0 = WsV[(k0 + 0) * 16 + l];
        float4 w1 = WsV[(k0 + 1) * 16 + l];
        float4 w2 = WsV[(k0 + 2) * 16 + l];
        float4 w3 = WsV[(k0 + 3) * 16 + l];
        yp.x = fmaf(a0, w0.x, yp.x); yp.y = fmaf(a0, w0.y, yp.y);
        yp.z = fmaf(a0, w0.z, yp.z); yp.w = fmaf(a0, w0.w, yp.w);
        yp.x = fmaf(a1, w1.x, yp.x); yp.y = fmaf(a1, w1.y, yp.y);
        yp.z = fmaf(a1, w1.z, yp.z); yp.w = fmaf(a1, w1.w, yp.w);
        yp.x = fmaf(a2, w2.x, yp.x); yp.y = fmaf(a2, w2.y, yp.y);
        yp.z = fmaf(a2, w2.z, yp.z); yp.w = fmaf(a2, w2.w, yp.w);
        yp.x = fmaf(a3, w3.x, yp.x); yp.y = fmaf(a3, w3.y, yp.y);
        yp.z = fmaf(a3, w3.z, yp.z); yp.w = fmaf(a3, w3.w, yp.w);
    }
    yp.x += __shfl_xor(yp.x, 16, 64); yp.y += __shfl_xor(yp.y, 16, 64);
    yp.z += __shfl_xor(yp.z, 16, 64); yp.w += __shfl_xor(yp.w, 16, 64);
    yp.x += __shfl_xor(yp.x, 32, 64); yp.y += __shfl_xor(yp.y, 32, 64);
    yp.z += __shfl_xor(yp.z, 32, 64); yp.w += __shfl_xor(yp.w, 32, 64);

    float4 bias = ((const float4*)b)[l];
    float4 yv;
    yv.x = yp.x + bias.x; yv.y = yp.y + bias.y;
    yv.z = yp.z + bias.z; yv.w = yp.w + bias.w;
    if (relu_flag) {
        yv.x = fmaxf(yv.x, 0.f); yv.y = fmaxf(yv.y, 0.f);
        yv.z = fmaxf(yv.z, 0.f); yv.w = fmaxf(yv.w, 0.f);
    }
    if (g == 0) {
        y[(size_t)node * 16 + l] = enc4(yv);
        ((float4*)&ps1[wave][0])[l] = yv;
        float4 sq;
        sq.x = yv.x * yv.x; sq.y = yv.y * yv.y;
        sq.z = yv.z * yv.z; sq.w = yv.w * yv.w;
        ((float4*)&ps2[wave][0])[l] = sq;
    }
    __syncthreads();
    if (tid < FD) {
        float a = ps1[0][tid] + ps1[1][tid] + ps1[2][tid] + ps1[3][tid];
        float q = ps2[0][tid] + ps2[1][tid] + ps2[2][tid] + ps2[3][tid];
        float* bk = buckets + (blockIdx.x & 63) * 128;
        atomicAdd(&bk[tid], a);
        atomicAdd(&bk[FD + tid], q);
    }
}

// ---------------- fused pool + head (prologue computes BN3 affine) --------
__global__ __launch_bounds__(256) void pool_head_kernel(
    const uint2* __restrict__ y, const int* __restrict__ batch,
    const float* __restrict__ buckets3,
    const float* __restrict__ g3, const float* __restrict__ be3,
    const float* __restrict__ fcW1, const float* __restrict__ fcb1,
    const float* __restrict__ fcW2, const float* __restrict__ fcb2,
    float* __restrict__ out)
{
    __shared__ float red[16][FD];
    __shared__ float afs[FD], cfs[FD];
    __shared__ int bounds[2];
    int tid = threadIdx.x;
    int g = blockIdx.x;

    // prologue: BN3 affine from buckets3
    {
        int f = tid & 63, q = tid >> 6;
        float S1 = 0.f, S2 = 0.f;
        #pragma unroll
        for (int i = 0; i < 16; i++) {
            int bkt = q * 16 + i;
            S1 += buckets3[bkt * 128 + f];
            S2 += buckets3[bkt * 128 + FD + f];
        }
        red[q][f]     = S1;
        red[4 + q][f] = S2;
    }
    if (tid < 2) {
        int target = g + tid;           // lower_bound(batch, target)
        int lo = 0, hi = NN;
        while (lo < hi) {
            int mid = (lo + hi) >> 1;
            if (batch[mid] < target) lo = mid + 1; else hi = mid;
        }
        bounds[tid] = lo;
    }
    __syncthreads();
    if (tid < FD) {
        float s1 = red[0][tid] + red[1][tid] + red[2][tid] + red[3][tid];
        float s2 = red[4][tid] + red[5][tid] + red[6][tid] + red[7][tid];
        float mu  = s1 * (1.f / NN);
        float var = s2 * (1.f / NN) - mu * mu;
        float a = g3[tid] * rsqrtf(var + BN_EPS);
        afs[tid] = a;
        cfs[tid] = be3[tid] - mu * a;
    }
    __syncthreads();

    int s = bounds[0], e = bounds[1];
    int l = tid & 15, r = tid >> 4;
    float4 acc = make_float4(0.f, 0.f, 0.f, 0.f);
    for (int n = s + r; n < e; n += 16) {
        float4 v = dec4(y[(size_t)n * 16 + l]);
        acc.x += v.x; acc.y += v.y; acc.z += v.z; acc.w += v.w;
    }
    ((float4*)&red[r][0])[l] = acc;
    __syncthreads();
    for (int off = 8; off > 0; off >>= 1) {
        if (r < off) {
            float4 a = ((float4*)&red[r][0])[l];
            float4 o = ((float4*)&red[r + off][0])[l];
            a.x += o.x; a.y += o.y; a.z += o.z; a.w += o.w;
            ((float4*)&red[r][0])[l] = a;
        }
        __syncthreads();
    }
    if (tid < 64) {                      // wave-uniform branch: shuffles safe
        float cnt = (float)(e - s);
        float p = red[0][tid];
        p = fmaf(afs[tid], p, cfs[tid] * cnt);  // BN3
        p = fmaxf(p, 0.f);
        float acc1 = fcb1[tid];
        #pragma unroll
        for (int k = 0; k < FD; k++) {
            float pk = __shfl(p, k, 64);
            acc1 = fmaf(pk, fcW1[k * FD + tid], acc1);
        }
        acc1 = fmaxf(acc1, 0.f);
        float prod = acc1 * fcW2[tid];
        #pragma unroll
        for (int off = 32; off > 0; off >>= 1)
            prod += __shfl_xor(prod, off, 64);
        if (tid == 0) out[g] = prod + fcb2[0];
    }
}

extern "C" void kernel_launch(void* const* d_in, const int* in_sizes, int n_in,
                              void* d_out, int out_size, void* d_ws, size_t ws_size,
                              hipStream_t stream) {
    const float* x     = (const float*)d_in[0];
    const int*   ei    = (const int*)d_in[1];
    const float* ew    = (const float*)d_in[2];
    const int*   batch = (const int*)d_in[3];
    const float* W1 = (const float*)d_in[4],  *b1 = (const float*)d_in[5];
    const float* W2 = (const float*)d_in[6],  *b2 = (const float*)d_in[7];
    const float* W3 = (const float*)d_in[8],  *b3 = (const float*)d_in[9];
    const float* fcW1 = (const float*)d_in[10], *fcb1 = (const float*)d_in[11];
    const float* fcW2 = (const float*)d_in[12], *fcb2 = (const float*)d_in[13];
    const float* g1 = (const float*)d_in[14], *be1 = (const float*)d_in[15];
    const float* g2 = (const float*)d_in[16], *be2 = (const float*)d_in[17];
    const float* g3 = (const float*)d_in[18], *be3 = (const float*)d_in[19];
    float* out = (float*)d_out;

    const int* srcp = ei;
    const int* dstp = ei + NE;

    char* ws = (char*)d_ws;
    size_t off = 0;
    auto take = [&](size_t bytes) -> char* {
        char* p = ws + off;
        off += (bytes + 255) & ~(size_t)255;
        return p;
    };
    uint2*    xbf   = (uint2*)   take((size_t)NN * FD * 2);    // 6.4 MB
    uint2*    bufA  = (uint2*)   take((size_t)NN * FD * 2);    // y1, then y3
    uint2*    bufB  = (uint2*)   take((size_t)NN * FD * 2);    // y2
    unsigned* slots = (unsigned*)take((size_t)NN * CAP * 4);   // 12.8 MB
    size_t zero_base = off;
    int*      cursor= (int*)     take((size_t)NN * 4);         // becomes deg
    float*    buckets=(float*)   take((size_t)3 * 64 * 128 * 4);
    size_t zero_bytes = off - zero_base;
    (void)ws_size; (void)n_in; (void)in_sizes; (void)out_size;

    hipMemsetAsync(ws + zero_base, 0, zero_bytes, stream);

    build_cvt_kernel<<<NBUILD + NCVT, 256, 0, stream>>>(srcp, dstp, ew,
                                                        cursor, slots,
                                                        (const float4*)x, xbf);

    const int gridA = NN / 4;   // 12500 blocks, 4 nodes (waves) each

    float* bk1 = buckets + 0 * 64 * 128;
    float* bk2 = buckets + 1 * 64 * 128;
    float* bk3 = buckets + 2 * 64 * 128;

    agg_layer_kernel<<<gridA, 256, 0, stream>>>(xbf, cursor, slots,
                                                nullptr, nullptr, nullptr,
                                                W1, b1, bufA, bk1, 1);
    agg_layer_kernel<<<gridA, 256, 0, stream>>>(bufA, cursor, slots,
                                                bk1, g1, be1,
                                                W2, b2, bufB, bk2, 1);
    agg_layer_kernel<<<gridA, 256, 0, stream>>>(bufB, cursor, slots,
                                                bk2, g2, be2,
                                                W3, b3, bufA, bk3, 0);
    pool_head_kernel<<<NG, 256, 0, stream>>>(bufA, batch, bk3, g3, be3,
                                             fcW1, fcb1, fcW2, fcb2, out);
}

// Round 14
// 269.129 us; speedup vs baseline: 11.5424x; 1.0064x over previous
//
#include <hip/hip_runtime.h>
#include <hip/hip_bf16.h>

// GIN GNN forward, R14 = R13 +
// 1) pre-masked slot table: slots zero-filled before build, so unused
//    entries decode to (src=0, w=0). Edge loop loses ALL masks/clamps
//    (~25% of edge-phase VALU; agg is VALU-bound at 54%).
// 2) stats buckets 64 -> 16: prologue bucket re-read 16KB -> 4KB per block
//    (200 -> 50 MB L2 traffic per agg dispatch).

#define NN 50000
#define NE 800000
#define FD 64
#define NG 256
#define CAP 64            // slots per node == wave width; max degree ~42
#define NBKT 16           // stats buckets
#define BN_EPS 1e-5f

#define NPART 8
#define PSIZE 6250        // nodes per XCD partition
#define ECHUNK 2048       // edges per build block
#define NCHUNK ((NE + ECHUNK - 1) / ECHUNK)     // 391
#define NBUILD (NCHUNK * NPART)                 // 3128
#define NCVT   ((NN * 16) / 256)                // 3125

__device__ __forceinline__ float4 dec4(uint2 a) {
    float4 f;
    f.x = __uint_as_float(a.x << 16);
    f.y = __uint_as_float(a.x & 0xFFFF0000u);
    f.z = __uint_as_float(a.y << 16);
    f.w = __uint_as_float(a.y & 0xFFFF0000u);
    return f;
}
__device__ __forceinline__ unsigned rbf(float f) {   // f32 -> bf16 bits (RNE)
    unsigned u = __float_as_uint(f);
    return (u + 0x7FFFu + ((u >> 16) & 1u)) >> 16;
}
__device__ __forceinline__ uint2 enc4(float4 v) {
    uint2 o;
    o.x = rbf(v.x) | (rbf(v.y) << 16);
    o.y = rbf(v.z) | (rbf(v.w) << 16);
    return o;
}

// ---------------- fused: XCD-partitioned slot build + x->bf16 cvt ----------
__global__ __launch_bounds__(256) void build_cvt_kernel(
    const int* __restrict__ src, const int* __restrict__ dst,
    const float* __restrict__ ew, int* __restrict__ cursor,
    unsigned* __restrict__ slots,
    const float4* __restrict__ xin, uint2* __restrict__ xout)
{
    int bid = blockIdx.x;
    int tid = threadIdx.x;
    if (bid < NBUILD) {
        int part  = bid & 7;            // consecutive blocks -> different XCDs
        int chunk = bid >> 3;
        int base  = chunk * ECHUNK;
        #pragma unroll
        for (int i = 0; i < ECHUNK; i += 256) {
            int e = base + i + tid;
            if (e < NE) {
                int d = dst[e];
                if (d / PSIZE == part) {    // this XCD owns this dst slice
                    int pos = atomicAdd(&cursor[d], 1) & (CAP - 1);
                    slots[(size_t)d * CAP + pos] =
                        ((unsigned)src[e] << 16) | rbf(ew[e]);
                }
            }
        }
    } else {
        int i = (bid - NBUILD) * 256 + tid;   // NN*16 = 800000 exact
        xout[i] = enc4(xin[i]);
    }
}

// ---------------- fused layer (+ prologue BN affine of PREV layer) --------
// 1 node per wave; lane = (g = edge group, l = feature quad).
// Slots pre-masked: entries >= deg have w=0, src=0 -> NO masks needed.
__global__ __launch_bounds__(256) void agg_layer_kernel(
    const uint2* __restrict__ h, const int* __restrict__ deg,
    const unsigned* __restrict__ slots,
    const float* __restrict__ prev_buckets,     // null for layer 1
    const float* __restrict__ prev_gamma, const float* __restrict__ prev_beta,
    const float* __restrict__ W, const float* __restrict__ b,
    uint2* __restrict__ y, float* __restrict__ buckets, int relu_flag)
{
    __shared__ float Ws[FD * FD];       // 16 KB
    __shared__ float ps1[4][FD];
    __shared__ float ps2[4][FD];
    __shared__ float afs[FD], cfs[FD];
    int tid  = threadIdx.x;
    int wave = tid >> 6, lane = tid & 63;
    int g = lane >> 4, l = lane & 15;
    int node = blockIdx.x * 4 + wave;   // 12500 * 4 == NN exact

    // stage W into LDS (coalesced float4)
    {
        float4* Wv = (float4*)Ws;
        const float4* Wg = (const float4*)W;
        #pragma unroll
        for (int i = 0; i < 4; i++) Wv[tid + 256 * i] = Wg[tid + 256 * i];
    }

    // slot row register-resident: lane i holds entry i (4B each)
    unsigned ms = slots[(size_t)node * CAP + lane];
    int dg = deg[node];                 // wave-uniform
    float4 self = dec4(h[(size_t)node * 16 + l]);
    if (dg > CAP) dg = CAP;

    // prologue: reduce prev layer's 16 buckets -> BN affine
    if (prev_buckets) {
        int f = tid & 63, q = tid >> 6;
        float S1 = 0.f, S2 = 0.f;
        #pragma unroll
        for (int i = 0; i < 4; i++) {
            int bkt = q * 4 + i;
            S1 += prev_buckets[bkt * 128 + f];
            S2 += prev_buckets[bkt * 128 + FD + f];
        }
        ps1[q][f] = S1;
        ps2[q][f] = S2;
    }
    __syncthreads();
    if (prev_buckets && tid < FD) {
        float s1 = ps1[0][tid] + ps1[1][tid] + ps1[2][tid] + ps1[3][tid];
        float s2 = ps2[0][tid] + ps2[1][tid] + ps2[2][tid] + ps2[3][tid];
        float mu  = s1 * (1.f / NN);
        float var = s2 * (1.f / NN) - mu * mu;
        float a = prev_gamma[tid] * rsqrtf(var + BN_EPS);
        afs[tid] = a;
        cfs[tid] = prev_beta[tid] - mu * a;
    }
    __syncthreads();

    float4 af = make_float4(1.f, 1.f, 1.f, 1.f);
    float4 cf = make_float4(0.f, 0.f, 0.f, 0.f);
    if (prev_buckets) {
        af = ((const float4*)afs)[l];
        cf = ((const float4*)cfs)[l];
    }

    float4 acc = make_float4(0.f, 0.f, 0.f, 0.f);
    float wsum = 0.f;
    if (dg <= 16) {
        // single 16-edge pass: no masks (padding has w=0)
        unsigned m[4]; uint2 r[4];
        #pragma unroll
        for (int j = 0; j < 4; j++)
            m[j] = (unsigned)__shfl((int)ms, 4 * j + g, 64);
        #pragma unroll
        for (int j = 0; j < 4; j++)
            r[j] = h[(size_t)(m[j] >> 16) * 16 + l];
        #pragma unroll
        for (int j = 0; j < 4; j++) {
            float w = __uint_as_float(m[j] << 16);
            float4 v = dec4(r[j]);
            wsum += w;
            acc.x = fmaf(w, v.x, acc.x); acc.y = fmaf(w, v.y, acc.y);
            acc.z = fmaf(w, v.z, acc.z); acc.w = fmaf(w, v.w, acc.w);
        }
    } else {
        int nIter = (dg + 31) >> 5;     // WAVE-UNIFORM; 32 edges per iter
        for (int i = 0; i < nIter; i++) {
            unsigned m[8]; uint2 r[8];
            #pragma unroll
            for (int j = 0; j < 8; j++)
                m[j] = (unsigned)__shfl((int)ms, 32 * i + 4 * j + g, 64);
            #pragma unroll
            for (int j = 0; j < 8; j++)  // 8 independent gathers in flight
                r[j] = h[(size_t)(m[j] >> 16) * 16 + l];
            #pragma unroll
            for (int j = 0; j < 8; j++) {
                float w = __uint_as_float(m[j] << 16);
                float4 v = dec4(r[j]);
                wsum += w;
                acc.x = fmaf(w, v.x, acc.x); acc.y = fmaf(w, v.y, acc.y);
                acc.z = fmaf(w, v.z, acc.z); acc.w = fmaf(w, v.w, acc.w);
            }
        }
    }
    // reduce across the 4 edge groups -> replicated in all lanes
    acc.x += __shfl_xor(acc.x, 16, 64); acc.y += __shfl_xor(acc.y, 16, 64);
    acc.z += __shfl_xor(acc.z, 16, 64); acc.w += __shfl_xor(acc.w, 16, 64);
    wsum  += __shfl_xor(wsum, 16, 64);
    acc.x += __shfl_xor(acc.x, 32, 64); acc.y += __shfl_xor(acc.y, 32, 64);
    acc.z += __shfl_xor(acc.z, 32, 64); acc.w += __shfl_xor(acc.w, 32, 64);
    wsum  += __shfl_xor(wsum, 32, 64);

    float4 raw;
    raw.x = self.x + acc.x; raw.y = self.y + acc.y;
    raw.z = self.z + acc.z; raw.w = self.w + acc.w;

    float sw = 1.0f + wsum;
    float4 hin;
    hin.x = fmaf(af.x, raw.x, cf.x * sw);
    hin.y = fmaf(af.y, raw.y, cf.y * sw);
    hin.z = fmaf(af.z, raw.z, cf.z * sw);
    hin.w = fmaf(af.w, raw.w, cf.w * sw);

    // matvec: group g covers k in [16g, 16g+16); W rows from LDS
    const float4* __restrict__ WsV = (const float4*)Ws;
    float4 yp = make_float4(0.f, 0.f, 0.f, 0.f);
    #pragma unroll
    for (int kk = 0; kk < 4; kk++) {
        int srcl = 4 * g + kk;           // lane holding features 4*srcl..+3
        float a0 = __shfl(hin.x, srcl, 64);
        float a1 = __shfl(hin.y, srcl, 64);
        float a2 = __shfl(hin.z, srcl, 64);
        float a3 = __shfl(hin.w, srcl, 64);
        int k0 = 16 * g + 4 * kk;
        float4 w0 = WsV[(k0 + 0) * 16 + l];
        float4 w1 = WsV[(k0 + 1) * 16 + l];
        float4 w2 = WsV[(k0 + 2) * 16 + l];
        float4 w3 = WsV[(k0 + 3) * 16 + l];
        yp.x = fmaf(a0, w0.x, yp.x); yp.y = fmaf(a0, w0.y, yp.y);
        yp.z = fmaf(a0, w0.z, yp.z); yp.w = fmaf(a0, w0.w, yp.w);
        yp.x = fmaf(a1, w1.x, yp.x); yp.y = fmaf(a1, w1.y, yp.y);
        yp.z = fmaf(a1, w1.z, yp.z); yp.w = fmaf(a1, w1.w, yp.w);
        yp.x = fmaf(a2, w2.x, yp.x); yp.y = fmaf(a2, w2.y, yp.y);
        yp.z = fmaf(a2, w2.z, yp.z); yp.w = fmaf(a2, w2.w, yp.w);
        yp.x = fmaf(a3, w3.x, yp.x); yp.y = fmaf(a3, w3.y, yp.y);
        yp.z = fmaf(a3, w3.z, yp.z); yp.w = fmaf(a3, w3.w, yp.w);
    }
    yp.x += __shfl_xor(yp.x, 16, 64); yp.y += __shfl_xor(yp.y, 16, 64);
    yp.z += __shfl_xor(yp.z, 16, 64); yp.w += __shfl_xor(yp.w, 16, 64);
    yp.x += __shfl_xor(yp.x, 32, 64); yp.y += __shfl_xor(yp.y, 32, 64);
    yp.z += __shfl_xor(yp.z, 32, 64); yp.w += __shfl_xor(yp.w, 32, 64);

    float4 bias = ((const float4*)b)[l];
    float4 yv;
    yv.x = yp.x + bias.x; yv.y = yp.y + bias.y;
    yv.z = yp.z + bias.z; yv.w = yp.w + bias.w;
    if (relu_flag) {
        yv.x = fmaxf(yv.x, 0.f); yv.y = fmaxf(yv.y, 0.f);
        yv.z = fmaxf(yv.z, 0.f); yv.w = fmaxf(yv.w, 0.f);
    }
    if (g == 0) {
        y[(size_t)node * 16 + l] = enc4(yv);
        ((float4*)&ps1[wave][0])[l] = yv;
        float4 sq;
        sq.x = yv.x * yv.x; sq.y = yv.y * yv.y;
        sq.z = yv.z * yv.z; sq.w = yv.w * yv.w;
        ((float4*)&ps2[wave][0])[l] = sq;
    }
    __syncthreads();
    if (tid < FD) {
        float a = ps1[0][tid] + ps1[1][tid] + ps1[2][tid] + ps1[3][tid];
        float q = ps2[0][tid] + ps2[1][tid] + ps2[2][tid] + ps2[3][tid];
        float* bk = buckets + (blockIdx.x & (NBKT - 1)) * 128;
        atomicAdd(&bk[tid], a);
        atomicAdd(&bk[FD + tid], q);
    }
}

// ---------------- fused pool + head (prologue computes BN3 affine) --------
__global__ __launch_bounds__(256) void pool_head_kernel(
    const uint2* __restrict__ y, const int* __restrict__ batch,
    const float* __restrict__ buckets3,
    const float* __restrict__ g3, const float* __restrict__ be3,
    const float* __restrict__ fcW1, const float* __restrict__ fcb1,
    const float* __restrict__ fcW2, const float* __restrict__ fcb2,
    float* __restrict__ out)
{
    __shared__ float red[16][FD];
    __shared__ float afs[FD], cfs[FD];
    __shared__ int bounds[2];
    int tid = threadIdx.x;
    int g = blockIdx.x;

    // prologue: BN3 affine from buckets3
    {
        int f = tid & 63, q = tid >> 6;
        float S1 = 0.f, S2 = 0.f;
        #pragma unroll
        for (int i = 0; i < 4; i++) {
            int bkt = q * 4 + i;
            S1 += buckets3[bkt * 128 + f];
            S2 += buckets3[bkt * 128 + FD + f];
        }
        red[q][f]     = S1;
        red[4 + q][f] = S2;
    }
    if (tid < 2) {
        int target = g + tid;           // lower_bound(batch, target)
        int lo = 0, hi = NN;
        while (lo < hi) {
            int mid = (lo + hi) >> 1;
            if (batch[mid] < target) lo = mid + 1; else hi = mid;
        }
        bounds[tid] = lo;
    }
    __syncthreads();
    if (tid < FD) {
        float s1 = red[0][tid] + red[1][tid] + red[2][tid] + red[3][tid];
        float s2 = red[4][tid] + red[5][tid] + red[6][tid] + red[7][tid];
        float mu  = s1 * (1.f / NN);
        float var = s2 * (1.f / NN) - mu * mu;
        float a = g3[tid] * rsqrtf(var + BN_EPS);
        afs[tid] = a;
        cfs[tid] = be3[tid] - mu * a;
    }
    __syncthreads();

    int s = bounds[0], e = bounds[1];
    int l = tid & 15, r = tid >> 4;
    float4 acc = make_float4(0.f, 0.f, 0.f, 0.f);
    for (int n = s + r; n < e; n += 16) {
        float4 v = dec4(y[(size_t)n * 16 + l]);
        acc.x += v.x; acc.y += v.y; acc.z += v.z; acc.w += v.w;
    }
    ((float4*)&red[r][0])[l] = acc;
    __syncthreads();
    for (int off = 8; off > 0; off >>= 1) {
        if (r < off) {
            float4 a = ((float4*)&red[r][0])[l];
            float4 o = ((float4*)&red[r + off][0])[l];
            a.x += o.x; a.y += o.y; a.z += o.z; a.w += o.w;
            ((float4*)&red[r][0])[l] = a;
        }
        __syncthreads();
    }
    if (tid < 64) {                      // wave-uniform branch: shuffles safe
        float cnt = (float)(e - s);
        float p = red[0][tid];
        p = fmaf(afs[tid], p, cfs[tid] * cnt);  // BN3
        p = fmaxf(p, 0.f);
        float acc1 = fcb1[tid];
        #pragma unroll
        for (int k = 0; k < FD; k++) {
            float pk = __shfl(p, k, 64);
            acc1 = fmaf(pk, fcW1[k * FD + tid], acc1);
        }
        acc1 = fmaxf(acc1, 0.f);
        float prod = acc1 * fcW2[tid];
        #pragma unroll
        for (int off = 32; off > 0; off >>= 1)
            prod += __shfl_xor(prod, off, 64);
        if (tid == 0) out[g] = prod + fcb2[0];
    }
}

extern "C" void kernel_launch(void* const* d_in, const int* in_sizes, int n_in,
                              void* d_out, int out_size, void* d_ws, size_t ws_size,
                              hipStream_t stream) {
    const float* x     = (const float*)d_in[0];
    const int*   ei    = (const int*)d_in[1];
    const float* ew    = (const float*)d_in[2];
    const int*   batch = (const int*)d_in[3];
    const float* W1 = (const float*)d_in[4],  *b1 = (const float*)d_in[5];
    const float* W2 = (const float*)d_in[6],  *b2 = (const float*)d_in[7];
    const float* W3 = (const float*)d_in[8],  *b3 = (const float*)d_in[9];
    const float* fcW1 = (const float*)d_in[10], *fcb1 = (const float*)d_in[11];
    const float* fcW2 = (const float*)d_in[12], *fcb2 = (const float*)d_in[13];
    const float* g1 = (const float*)d_in[14], *be1 = (const float*)d_in[15];
    const float* g2 = (const float*)d_in[16], *be2 = (const float*)d_in[17];
    const float* g3 = (const float*)d_in[18], *be3 = (const float*)d_in[19];
    float* out = (float*)d_out;

    const int* srcp = ei;
    const int* dstp = ei + NE;

    char* ws = (char*)d_ws;
    size_t off = 0;
    auto take = [&](size_t bytes) -> char* {
        char* p = ws + off;
        off += (bytes + 255) & ~(size_t)255;
        return p;
    };
    uint2*    xbf   = (uint2*)   take((size_t)NN * FD * 2);    // 6.4 MB
    uint2*    bufA  = (uint2*)   take((size_t)NN * FD * 2);    // y1, then y3
    uint2*    bufB  = (uint2*)   take((size_t)NN * FD * 2);    // y2
    size_t zero_base = off;
    unsigned* slots = (unsigned*)take((size_t)NN * CAP * 4);   // 12.8 MB, pre-masked
    int*      cursor= (int*)     take((size_t)NN * 4);         // becomes deg
    float*    buckets=(float*)   take((size_t)3 * NBKT * 128 * 4);
    size_t zero_bytes = off - zero_base;
    (void)ws_size; (void)n_in; (void)in_sizes; (void)out_size;

    hipMemsetAsync(ws + zero_base, 0, zero_bytes, stream);

    build_cvt_kernel<<<NBUILD + NCVT, 256, 0, stream>>>(srcp, dstp, ew,
                                                        cursor, slots,
                                                        (const float4*)x, xbf);

    const int gridA = NN / 4;   // 12500 blocks, 4 nodes (waves) each

    float* bk1 = buckets + 0 * NBKT * 128;
    float* bk2 = buckets + 1 * NBKT * 128;
    float* bk3 = buckets + 2 * NBKT * 128;

    agg_layer_kernel<<<gridA, 256, 0, stream>>>(xbf, cursor, slots,
                                                nullptr, nullptr, nullptr,
                                                W1, b1, bufA, bk1, 1);
    agg_layer_kernel<<<gridA, 256, 0, stream>>>(bufA, cursor, slots,
                                                bk1, g1, be1,
                                                W2, b2, bufB, bk2, 1);
    agg_layer_kernel<<<gridA, 256, 0, stream>>>(bufB, cursor, slots,
                                                bk2, g2, be2,
                                                W3, b3, bufA, bk3, 0);
    pool_head_kernel<<<NG, 256, 0, stream>>>(bufA, batch, bk3, g3, be3,
                                             fcW1, fcb1, fcW2, fcb2, out);
}

// Round 15
// 263.998 us; speedup vs baseline: 11.7667x; 1.0194x over previous
//
#include <hip/hip_runtime.h>
#include <hip/hip_bf16.h>

// GIN GNN forward, R15 = R14 with pure x4 unmasked edge loop (16 edges/iter).
// Hybrid/x8 variants measured neutral (R12/R13); pure x4 was the best-ever
// loop shape (R10, 265us). Pre-masked slot table keeps the loop mask-free.

#define NN 50000
#define NE 800000
#define FD 64
#define NG 256
#define CAP 64            // slots per node == wave width; max degree ~42
#define NBKT 16           // stats buckets
#define BN_EPS 1e-5f

#define NPART 8
#define PSIZE 6250        // nodes per XCD partition
#define ECHUNK 2048       // edges per build block
#define NCHUNK ((NE + ECHUNK - 1) / ECHUNK)     // 391
#define NBUILD (NCHUNK * NPART)                 // 3128
#define NCVT   ((NN * 16) / 256)                // 3125

__device__ __forceinline__ float4 dec4(uint2 a) {
    float4 f;
    f.x = __uint_as_float(a.x << 16);
    f.y = __uint_as_float(a.x & 0xFFFF0000u);
    f.z = __uint_as_float(a.y << 16);
    f.w = __uint_as_float(a.y & 0xFFFF0000u);
    return f;
}
__device__ __forceinline__ unsigned rbf(float f) {   // f32 -> bf16 bits (RNE)
    unsigned u = __float_as_uint(f);
    return (u + 0x7FFFu + ((u >> 16) & 1u)) >> 16;
}
__device__ __forceinline__ uint2 enc4(float4 v) {
    uint2 o;
    o.x = rbf(v.x) | (rbf(v.y) << 16);
    o.y = rbf(v.z) | (rbf(v.w) << 16);
    return o;
}

// ---------------- fused: XCD-partitioned slot build + x->bf16 cvt ----------
__global__ __launch_bounds__(256) void build_cvt_kernel(
    const int* __restrict__ src, const int* __restrict__ dst,
    const float* __restrict__ ew, int* __restrict__ cursor,
    unsigned* __restrict__ slots,
    const float4* __restrict__ xin, uint2* __restrict__ xout)
{
    int bid = blockIdx.x;
    int tid = threadIdx.x;
    if (bid < NBUILD) {
        int part  = bid & 7;            // consecutive blocks -> different XCDs
        int chunk = bid >> 3;
        int base  = chunk * ECHUNK;
        #pragma unroll
        for (int i = 0; i < ECHUNK; i += 256) {
            int e = base + i + tid;
            if (e < NE) {
                int d = dst[e];
                if (d / PSIZE == part) {    // this XCD owns this dst slice
                    int pos = atomicAdd(&cursor[d], 1) & (CAP - 1);
                    slots[(size_t)d * CAP + pos] =
                        ((unsigned)src[e] << 16) | rbf(ew[e]);
                }
            }
        }
    } else {
        int i = (bid - NBUILD) * 256 + tid;   // NN*16 = 800000 exact
        xout[i] = enc4(xin[i]);
    }
}

// ---------------- fused layer (+ prologue BN affine of PREV layer) --------
// 1 node per wave; lane = (g = edge group, l = feature quad).
// Slots pre-masked: entries >= deg have w=0, src=0 -> NO masks needed.
__global__ __launch_bounds__(256) void agg_layer_kernel(
    const uint2* __restrict__ h, const int* __restrict__ deg,
    const unsigned* __restrict__ slots,
    const float* __restrict__ prev_buckets,     // null for layer 1
    const float* __restrict__ prev_gamma, const float* __restrict__ prev_beta,
    const float* __restrict__ W, const float* __restrict__ b,
    uint2* __restrict__ y, float* __restrict__ buckets, int relu_flag)
{
    __shared__ float Ws[FD * FD];       // 16 KB
    __shared__ float ps1[4][FD];
    __shared__ float ps2[4][FD];
    __shared__ float afs[FD], cfs[FD];
    int tid  = threadIdx.x;
    int wave = tid >> 6, lane = tid & 63;
    int g = lane >> 4, l = lane & 15;
    int node = blockIdx.x * 4 + wave;   // 12500 * 4 == NN exact

    // stage W into LDS (coalesced float4)
    {
        float4* Wv = (float4*)Ws;
        const float4* Wg = (const float4*)W;
        #pragma unroll
        for (int i = 0; i < 4; i++) Wv[tid + 256 * i] = Wg[tid + 256 * i];
    }

    // slot row register-resident: lane i holds entry i (4B each)
    unsigned ms = slots[(size_t)node * CAP + lane];
    int dg = deg[node];                 // wave-uniform
    float4 self = dec4(h[(size_t)node * 16 + l]);
    if (dg > CAP) dg = CAP;

    // prologue: reduce prev layer's 16 buckets -> BN affine
    if (prev_buckets) {
        int f = tid & 63, q = tid >> 6;
        float S1 = 0.f, S2 = 0.f;
        #pragma unroll
        for (int i = 0; i < 4; i++) {
            int bkt = q * 4 + i;
            S1 += prev_buckets[bkt * 128 + f];
            S2 += prev_buckets[bkt * 128 + FD + f];
        }
        ps1[q][f] = S1;
        ps2[q][f] = S2;
    }
    __syncthreads();
    if (prev_buckets && tid < FD) {
        float s1 = ps1[0][tid] + ps1[1][tid] + ps1[2][tid] + ps1[3][tid];
        float s2 = ps2[0][tid] + ps2[1][tid] + ps2[2][tid] + ps2[3][tid];
        float mu  = s1 * (1.f / NN);
        float var = s2 * (1.f / NN) - mu * mu;
        float a = prev_gamma[tid] * rsqrtf(var + BN_EPS);
        afs[tid] = a;
        cfs[tid] = prev_beta[tid] - mu * a;
    }
    __syncthreads();

    float4 af = make_float4(1.f, 1.f, 1.f, 1.f);
    float4 cf = make_float4(0.f, 0.f, 0.f, 0.f);
    if (prev_buckets) {
        af = ((const float4*)afs)[l];
        cf = ((const float4*)cfs)[l];
    }

    float4 acc = make_float4(0.f, 0.f, 0.f, 0.f);
    float wsum = 0.f;
    int nIter = (dg + 15) >> 4;         // WAVE-UNIFORM; 16 edges per iter
    for (int i = 0; i < nIter; i++) {
        unsigned m[4]; uint2 r[4];
        #pragma unroll
        for (int j = 0; j < 4; j++)     // no masks: padding decodes to w=0
            m[j] = (unsigned)__shfl((int)ms, 16 * i + 4 * j + g, 64);
        #pragma unroll
        for (int j = 0; j < 4; j++)     // 4 independent gathers in flight
            r[j] = h[(size_t)(m[j] >> 16) * 16 + l];
        #pragma unroll
        for (int j = 0; j < 4; j++) {
            float w = __uint_as_float(m[j] << 16);
            float4 v = dec4(r[j]);
            wsum += w;
            acc.x = fmaf(w, v.x, acc.x); acc.y = fmaf(w, v.y, acc.y);
            acc.z = fmaf(w, v.z, acc.z); acc.w = fmaf(w, v.w, acc.w);
        }
    }
    // reduce across the 4 edge groups -> replicated in all lanes
    acc.x += __shfl_xor(acc.x, 16, 64); acc.y += __shfl_xor(acc.y, 16, 64);
    acc.z += __shfl_xor(acc.z, 16, 64); acc.w += __shfl_xor(acc.w, 16, 64);
    wsum  += __shfl_xor(wsum, 16, 64);
    acc.x += __shfl_xor(acc.x, 32, 64); acc.y += __shfl_xor(acc.y, 32, 64);
    acc.z += __shfl_xor(acc.z, 32, 64); acc.w += __shfl_xor(acc.w, 32, 64);
    wsum  += __shfl_xor(wsum, 32, 64);

    float4 raw;
    raw.x = self.x + acc.x; raw.y = self.y + acc.y;
    raw.z = self.z + acc.z; raw.w = self.w + acc.w;

    float sw = 1.0f + wsum;
    float4 hin;
    hin.x = fmaf(af.x, raw.x, cf.x * sw);
    hin.y = fmaf(af.y, raw.y, cf.y * sw);
    hin.z = fmaf(af.z, raw.z, cf.z * sw);
    hin.w = fmaf(af.w, raw.w, cf.w * sw);

    // matvec: group g covers k in [16g, 16g+16); W rows from LDS
    const float4* __restrict__ WsV = (const float4*)Ws;
    float4 yp = make_float4(0.f, 0.f, 0.f, 0.f);
    #pragma unroll
    for (int kk = 0; kk < 4; kk++) {
        int srcl = 4 * g + kk;           // lane holding features 4*srcl..+3
        float a0 = __shfl(hin.x, srcl, 64);
        float a1 = __shfl(hin.y, srcl, 64);
        float a2 = __shfl(hin.z, srcl, 64);
        float a3 = __shfl(hin.w, srcl, 64);
        int k0 = 16 * g + 4 * kk;
        float4 w0 = WsV[(k0 + 0) * 16 + l];
        float4 w1 = WsV[(k0 + 1) * 16 + l];
        float4 w2 = WsV[(k0 + 2) * 16 + l];
        float4 w3 = WsV[(k0 + 3) * 16 + l];
        yp.x = fmaf(a0, w0.x, yp.x); yp.y = fmaf(a0, w0.y, yp.y);
        yp.z = fmaf(a0, w0.z, yp.z); yp.w = fmaf(a0, w0.w, yp.w);
        yp.x = fmaf(a1, w1.x, yp.x); yp.y = fmaf(a1, w1.y, yp.y);
        yp.z = fmaf(a1, w1.z, yp.z); yp.w = fmaf(a1, w1.w, yp.w);
        yp.x = fmaf(a2, w2.x, yp.x); yp.y = fmaf(a2, w2.y, yp.y);
        yp.z = fmaf(a2, w2.z, yp.z); yp.w = fmaf(a2, w2.w, yp.w);
        yp.x = fmaf(a3, w3.x, yp.x); yp.y = fmaf(a3, w3.y, yp.y);
        yp.z = fmaf(a3, w3.z, yp.z); yp.w = fmaf(a3, w3.w, yp.w);
    }
    yp.x += __shfl_xor(yp.x, 16, 64); yp.y += __shfl_xor(yp.y, 16, 64);
    yp.z += __shfl_xor(yp.z, 16, 64); yp.w += __shfl_xor(yp.w, 16, 64);
    yp.x += __shfl_xor(yp.x, 32, 64); yp.y += __shfl_xor(yp.y, 32, 64);
    yp.z += __shfl_xor(yp.z, 32, 64); yp.w += __shfl_xor(yp.w, 32, 64);

    float4 bias = ((const float4*)b)[l];
    float4 yv;
    yv.x = yp.x + bias.x; yv.y = yp.y + bias.y;
    yv.z = yp.z + bias.z; yv.w = yp.w + bias.w;
    if (relu_flag) {
        yv.x = fmaxf(yv.x, 0.f); yv.y = fmaxf(yv.y, 0.f);
        yv.z = fmaxf(yv.z, 0.f); yv.w = fmaxf(yv.w, 0.f);
    }
    if (g == 0) {
        y[(size_t)node * 16 + l] = enc4(yv);
        ((float4*)&ps1[wave][0])[l] = yv;
        float4 sq;
        sq.x = yv.x * yv.x; sq.y = yv.y * yv.y;
        sq.z = yv.z * yv.z; sq.w = yv.w * yv.w;
        ((float4*)&ps2[wave][0])[l] = sq;
    }
    __syncthreads();
    if (tid < FD) {
        float a = ps1[0][tid] + ps1[1][tid] + ps1[2][tid] + ps1[3][tid];
        float q = ps2[0][tid] + ps2[1][tid] + ps2[2][tid] + ps2[3][tid];
        float* bk = buckets + (blockIdx.x & (NBKT - 1)) * 128;
        atomicAdd(&bk[tid], a);
        atomicAdd(&bk[FD + tid], q);
    }
}

// ---------------- fused pool + head (prologue computes BN3 affine) --------
__global__ __launch_bounds__(256) void pool_head_kernel(
    const uint2* __restrict__ y, const int* __restrict__ batch,
    const float* __restrict__ buckets3,
    const float* __restrict__ g3, const float* __restrict__ be3,
    const float* __restrict__ fcW1, const float* __restrict__ fcb1,
    const float* __restrict__ fcW2, const float* __restrict__ fcb2,
    float* __restrict__ out)
{
    __shared__ float red[16][FD];
    __shared__ float afs[FD], cfs[FD];
    __shared__ int bounds[2];
    int tid = threadIdx.x;
    int g = blockIdx.x;

    // prologue: BN3 affine from buckets3
    {
        int f = tid & 63, q = tid >> 6;
        float S1 = 0.f, S2 = 0.f;
        #pragma unroll
        for (int i = 0; i < 4; i++) {
            int bkt = q * 4 + i;
            S1 += buckets3[bkt * 128 + f];
            S2 += buckets3[bkt * 128 + FD + f];
        }
        red[q][f]     = S1;
        red[4 + q][f] = S2;
    }
    if (tid < 2) {
        int target = g + tid;           // lower_bound(batch, target)
        int lo = 0, hi = NN;
        while (lo < hi) {
            int mid = (lo + hi) >> 1;
            if (batch[mid] < target) lo = mid + 1; else hi = mid;
        }
        bounds[tid] = lo;
    }
    __syncthreads();
    if (tid < FD) {
        float s1 = red[0][tid] + red[1][tid] + red[2][tid] + red[3][tid];
        float s2 = red[4][tid] + red[5][tid] + red[6][tid] + red[7][tid];
        float mu  = s1 * (1.f / NN);
        float var = s2 * (1.f / NN) - mu * mu;
        float a = g3[tid] * rsqrtf(var + BN_EPS);
        afs[tid] = a;
        cfs[tid] = be3[tid] - mu * a;
    }
    __syncthreads();

    int s = bounds[0], e = bounds[1];
    int l = tid & 15, r = tid >> 4;
    float4 acc = make_float4(0.f, 0.f, 0.f, 0.f);
    for (int n = s + r; n < e; n += 16) {
        float4 v = dec4(y[(size_t)n * 16 + l]);
        acc.x += v.x; acc.y += v.y; acc.z += v.z; acc.w += v.w;
    }
    ((float4*)&red[r][0])[l] = acc;
    __syncthreads();
    for (int off = 8; off > 0; off >>= 1) {
        if (r < off) {
            float4 a = ((float4*)&red[r][0])[l];
            float4 o = ((float4*)&red[r + off][0])[l];
            a.x += o.x; a.y += o.y; a.z += o.z; a.w += o.w;
            ((float4*)&red[r][0])[l] = a;
        }
        __syncthreads();
    }
    if (tid < 64) {                      // wave-uniform branch: shuffles safe
        float cnt = (float)(e - s);
        float p = red[0][tid];
        p = fmaf(afs[tid], p, cfs[tid] * cnt);  // BN3
        p = fmaxf(p, 0.f);
        float acc1 = fcb1[tid];
        #pragma unroll
        for (int k = 0; k < FD; k++) {
            float pk = __shfl(p, k, 64);
            acc1 = fmaf(pk, fcW1[k * FD + tid], acc1);
        }
        acc1 = fmaxf(acc1, 0.f);
        float prod = acc1 * fcW2[tid];
        #pragma unroll
        for (int off = 32; off > 0; off >>= 1)
            prod += __shfl_xor(prod, off, 64);
        if (tid == 0) out[g] = prod + fcb2[0];
    }
}

extern "C" void kernel_launch(void* const* d_in, const int* in_sizes, int n_in,
                              void* d_out, int out_size, void* d_ws, size_t ws_size,
                              hipStream_t stream) {
    const float* x     = (const float*)d_in[0];
    const int*   ei    = (const int*)d_in[1];
    const float* ew    = (const float*)d_in[2];
    const int*   batch = (const int*)d_in[3];
    const float* W1 = (const float*)d_in[4],  *b1 = (const float*)d_in[5];
    const float* W2 = (const float*)d_in[6],  *b2 = (const float*)d_in[7];
    const float* W3 = (const float*)d_in[8],  *b3 = (const float*)d_in[9];
    const float* fcW1 = (const float*)d_in[10], *fcb1 = (const float*)d_in[11];
    const float* fcW2 = (const float*)d_in[12], *fcb2 = (const float*)d_in[13];
    const float* g1 = (const float*)d_in[14], *be1 = (const float*)d_in[15];
    const float* g2 = (const float*)d_in[16], *be2 = (const float*)d_in[17];
    const float* g3 = (const float*)d_in[18], *be3 = (const float*)d_in[19];
    float* out = (float*)d_out;

    const int* srcp = ei;
    const int* dstp = ei + NE;

    char* ws = (char*)d_ws;
    size_t off = 0;
    auto take = [&](size_t bytes) -> char* {
        char* p = ws + off;
        off += (bytes + 255) & ~(size_t)255;
        return p;
    };
    uint2*    xbf   = (uint2*)   take((size_t)NN * FD * 2);    // 6.4 MB
    uint2*    bufA  = (uint2*)   take((size_t)NN * FD * 2);    // y1, then y3
    uint2*    bufB  = (uint2*)   take((size_t)NN * FD * 2);    // y2
    size_t zero_base = off;
    unsigned* slots = (unsigned*)take((size_t)NN * CAP * 4);   // 12.8 MB, pre-masked
    int*      cursor= (int*)     take((size_t)NN * 4);         // becomes deg
    float*    buckets=(float*)   take((size_t)3 * NBKT * 128 * 4);
    size_t zero_bytes = off - zero_base;
    (void)ws_size; (void)n_in; (void)in_sizes; (void)out_size;

    hipMemsetAsync(ws + zero_base, 0, zero_bytes, stream);

    build_cvt_kernel<<<NBUILD + NCVT, 256, 0, stream>>>(srcp, dstp, ew,
                                                        cursor, slots,
                                                        (const float4*)x, xbf);

    const int gridA = NN / 4;   // 12500 blocks, 4 nodes (waves) each

    float* bk1 = buckets + 0 * NBKT * 128;
    float* bk2 = buckets + 1 * NBKT * 128;
    float* bk3 = buckets + 2 * NBKT * 128;

    agg_layer_kernel<<<gridA, 256, 0, stream>>>(xbf, cursor, slots,
                                                nullptr, nullptr, nullptr,
                                                W1, b1, bufA, bk1, 1);
    agg_layer_kernel<<<gridA, 256, 0, stream>>>(bufA, cursor, slots,
                                                bk1, g1, be1,
                                                W2, b2, bufB, bk2, 1);
    agg_layer_kernel<<<gridA, 256, 0, stream>>>(bufB, cursor, slots,
                                                bk2, g2, be2,
                                                W3, b3, bufA, bk3, 0);
    pool_head_kernel<<<NG, 256, 0, stream>>>(bufA, batch, bk3, g3, be3,
                                             fcW1, fcb1, fcW2, fcb2, out);
}